// Round 7
// baseline (879.383 us; speedup 1.0000x reference)
//
#include <hip/hip_runtime.h>
#include <stdint.h>

#define V 8192
#define C 128
#define KS 4
#define KCH (V / KS)   // 2048
#define BK 64
#define NI (KCH / BK)  // 32 k-tiles per chunk
#define NBLK 512       // 2 blocks/CU x 256 CUs: all co-resident

typedef __attribute__((ext_vector_type(8))) short short8;
typedef __attribute__((ext_vector_type(4))) float floatx4;

static __device__ __forceinline__ unsigned short f2bf(float f) {
    unsigned u = __float_as_uint(f);
    u += 0x7FFF + ((u >> 16) & 1);   // RNE
    return (unsigned short)(u >> 16);
}

static __device__ __forceinline__ void gload16(const void* g, void* l) {
    __builtin_amdgcn_global_load_lds(
        (const __attribute__((address_space(1))) void*)g,
        (__attribute__((address_space(3))) void*)l, 16, 0, 0);
}
#define SWAIT(s) asm volatile("s_waitcnt " s ::: "memory")
#define SBAR() __builtin_amdgcn_s_barrier()
#define SFENCE() __builtin_amdgcn_sched_barrier(0)

// producer: all threads' stores -> agent-visible, then one release-add
static __device__ __forceinline__ void block_signal(int* p) {
    __threadfence();
    __syncthreads();
    if (threadIdx.x == 0)
        __hip_atomic_fetch_add(p, 1, __ATOMIC_RELEASE, __HIP_MEMORY_SCOPE_AGENT);
}
// consumer: acquire-spin (bounded: bail -> wrong answer, never a hang)
static __device__ __forceinline__ void block_wait(int* p, int target) {
    if (threadIdx.x == 0) {
        int guard = 0;
        while (__hip_atomic_load(p, __ATOMIC_ACQUIRE, __HIP_MEMORY_SCOPE_AGENT) < target) {
            __builtin_amdgcn_s_sleep(2);
            if (++guard > (1 << 24)) break;
        }
    }
    __syncthreads();
    __threadfence();
}

__global__ __launch_bounds__(256, 2) void persist(const float* __restrict__ x,
                                                  const float* __restrict__ mass,
                                                  const float* __restrict__ E,
                                                  const float* __restrict__ ev0,
                                                  const float* __restrict__ ev1,
                                                  const float* __restrict__ dt,
                                                  unsigned short* __restrict__ XMT,
                                                  unsigned short* __restrict__ YT,
                                                  float* __restrict__ P1,
                                                  float* __restrict__ P2,
                                                  float* __restrict__ out,
                                                  int* __restrict__ cnt) {
    __shared__ __align__(16) unsigned short LBIG[2][128 * BK];  // 32 KB
    __shared__ __align__(16) unsigned short LSML[2][64 * BK];   // 16 KB
    __shared__ int s_old;

    const int bid = blockIdx.x;
    const int t = threadIdx.x;
    const int w = t >> 6, lane = t & 63, q = lane >> 4, l15 = lane & 15;
    const int lr = lane >> 3, lch = (lane & 7) ^ lr;
    const int ks = bid >> 7;           // k-chunk 0..3
    const int slab = bid & 127;        // 64-wide slab 0..127
    const int kb = ks * KCH;

    int* cnt_prep = cnt;
    int* cnt_col = cnt + 16;   // [4] gemm1 panels per column-chunk (target 128)
    int* cnt_yt = cnt + 32;    // [4] red1 slabs per chunk (target 32)
    int* cnt_m = cnt + 64;     // [128] gemm2 partials per m-slab (target 4)

    // ============ phase 0: prep XMT[c][k] = bf16(x[k][c]*mass[k]) ============
    if (bid < 256) {
        float* tile = (float*)&LBIG[0][0];  // 64*65 fp32 = 16.6 KB
        const int k0 = (bid >> 1) * 64;
        const int c0 = (bid & 1) * 64;
#pragma unroll
        for (int p = 0; p < 16; ++p) {
            int idx = p * 256 + t;
            int kk = idx >> 6, cc = idx & 63;
            tile[kk * 65 + cc] = x[(size_t)(k0 + kk) * C + (c0 + cc)] * mass[k0 + kk];
        }
        __syncthreads();
#pragma unroll
        for (int p = 0; p < 16; ++p) {
            int idx = p * 256 + t;
            int cc = idx >> 6, kk = idx & 63;
            XMT[(size_t)(c0 + cc) * V + (k0 + kk)] = f2bf(tile[kk * 65 + cc]);
        }
        block_signal(cnt_prep);
    }
    block_wait(cnt_prep, 256);

    // ============ phase 1: gemm1 — P1[ks][c][j], tile 128(C) x 64 ============
    {
        const int n0 = slab * 64;
        const int wm = (w & 1) * 64, wn = (w >> 1) * 32;
        const int jc = t & 15;     // E staging: cols jc*4..+3
        const int vg = t >> 4;     // E staging: rows vg*4..+3

        floatx4 acc[4][2] = {};
        float4 er0[4], er1[4];

#define G1_GLOADA(TI, BUF)                                                          \
    {                                                                               \
        const int kk_ = kb + (TI) * BK;                                             \
        _Pragma("unroll")                                                           \
        for (int i = 0; i < 4; ++i)                                                 \
            gload16(&XMT[(size_t)(i * 32 + w * 8 + lr) * V + kk_ + 8 * lch],        \
                    &LBIG[BUF][i * 2048 + w * 512]);                                \
    }
#define G1_ELOAD(ER, TI)                                                            \
    {                                                                               \
        const int kk_ = kb + (TI) * BK;                                             \
        _Pragma("unroll")                                                           \
        for (int u = 0; u < 4; ++u)                                                 \
            ER[u] = *(const float4*)&E[(size_t)(kk_ + vg * 4 + u) * V + n0 + jc * 4]; \
    }
#define G1_CONV(ER, BUF)                                                            \
    {                                                                               \
        _Pragma("unroll")                                                           \
        for (int jj = 0; jj < 4; ++jj) {                                            \
            const int j = jc * 4 + jj;                                              \
            ushort4 b;                                                              \
            b.x = f2bf(ER[0][jj]); b.y = f2bf(ER[1][jj]);                           \
            b.z = f2bf(ER[2][jj]); b.w = f2bf(ER[3][jj]);                           \
            *(ushort4*)&LSML[BUF][j * BK + ((vg >> 1) ^ (j & 7)) * 8 + (vg & 1) * 4] = b; \
        }                                                                           \
    }
#define G1_MFMA(pA, pB)                                                             \
    {                                                                               \
        _Pragma("unroll")                                                           \
        for (int kk = 0; kk < BK; kk += 32) {                                       \
            short8 af[4], bfv[2];                                                   \
            _Pragma("unroll")                                                       \
            for (int mi = 0; mi < 4; ++mi) {                                        \
                const int m = wm + mi * 16 + l15;                                   \
                af[mi] = *(const short8*)&pA[m * BK + 8 * (((kk >> 3) + q) ^ (m & 7))]; \
            }                                                                       \
            _Pragma("unroll")                                                       \
            for (int ni = 0; ni < 2; ++ni) {                                        \
                const int n = wn + ni * 16 + l15;                                   \
                bfv[ni] = *(const short8*)&pB[n * BK + 8 * (((kk >> 3) + q) ^ (n & 7))]; \
            }                                                                       \
            _Pragma("unroll")                                                       \
            for (int mi = 0; mi < 4; ++mi)                                          \
                _Pragma("unroll")                                                   \
                for (int ni = 0; ni < 2; ++ni)                                      \
                    acc[mi][ni] = __builtin_amdgcn_mfma_f32_16x16x32_bf16(          \
                        af[mi], bfv[ni], acc[mi][ni], 0, 0, 0);                     \
        }                                                                           \
    }

        G1_ELOAD(er0, 0);
        G1_GLOADA(0, 0);
        G1_ELOAD(er1, 1);
        G1_CONV(er0, 0);
        SWAIT("vmcnt(4) lgkmcnt(0)");
        SBAR();
        SFENCE();

#define G1_BODY(T, PF_ER, CV_ER)                                                    \
    {                                                                               \
        const int t1 = (T) + 1;                                                     \
        const int t2 = ((T) + 2 < NI) ? (T) + 2 : NI - 1;                           \
        const bool pf = t1 < NI;                                                    \
        if (pf) {                                                                   \
            G1_GLOADA(t1, cur ^ 1);                                                 \
            G1_ELOAD(PF_ER, t2);                                                    \
        }                                                                           \
        SFENCE();                                                                   \
        __builtin_amdgcn_s_setprio(1);                                              \
        G1_MFMA((&LBIG[cur][0]), (&LSML[cur][0]));                                  \
        __builtin_amdgcn_s_setprio(0);                                              \
        SFENCE();                                                                   \
        if (pf) {                                                                   \
            G1_CONV(CV_ER, cur ^ 1);                                                \
            SWAIT("vmcnt(4) lgkmcnt(0)");                                           \
            SBAR();                                                                 \
            SFENCE();                                                               \
            cur ^= 1;                                                               \
        }                                                                           \
    }

        int cur = 0;
        for (int tt = 0; tt < NI; tt += 2) {
            G1_BODY(tt, er0, er1);
            G1_BODY(tt + 1, er1, er0);
        }
#undef G1_BODY
#undef G1_MFMA
#undef G1_CONV
#undef G1_ELOAD
#undef G1_GLOADA

        float* Pks = P1 + (size_t)ks * C * V;
#pragma unroll
        for (int mi = 0; mi < 4; ++mi) {
            int mrow = wm + mi * 16 + q * 4;
#pragma unroll
            for (int ni = 0; ni < 2; ++ni) {
                int n = n0 + wn + ni * 16 + l15;
#pragma unroll
                for (int r = 0; r < 4; ++r)
                    Pks[(size_t)(mrow + r) * V + n] = acc[mi][ni][r];
            }
        }
    }
    block_signal(cnt_col + (slab >> 5));

    // ============ phase 2: red1 (ks==0 blocks; own 64-col slab) ============
    if (ks == 0) {
        block_wait(cnt_col + (slab >> 5), 128);
        const int j0s = slab * 64;
#pragma unroll
        for (int p = 0; p < 4; ++p) {
            const int u = t + 256 * p;          // 0..1023 = 128c x 8 j-blocks
            const int c = u >> 3;
            const int j0 = j0s + (u & 7) * 8;
            float s[8] = {};
#pragma unroll
            for (int kr = 0; kr < KS; ++kr) {
                const float* row = &P1[((size_t)kr * C + c) * V + j0];
                float4 a = *(const float4*)row;
                float4 b = *(const float4*)(row + 4);
                s[0] += a.x; s[1] += a.y; s[2] += a.z; s[3] += a.w;
                s[4] += b.x; s[5] += b.y; s[6] += b.z; s[7] += b.w;
            }
            const float t0 = dt[c], t1 = dt[C + c];
            const float a0 = ev0[j0 >> 7] * t0;
            short8 yv;
#pragma unroll
            for (int jj = 0; jj < 8; ++jj) {
                float coef = __expf(-(a0 + ev1[(j0 + jj) & 127] * t1));
                yv[jj] = (short)f2bf(s[jj] * coef);
            }
            *(short8*)&YT[(size_t)c * V + j0] = yv;
        }
        block_signal(cnt_yt + (slab >> 5));
    }

    // ============ phase 3: gemm2 — P2[ks][i][c], tile 64 x 128(C) ============
    block_wait(cnt_yt + ks, 32);
    {
        const int m0 = slab * 64;
        const int wm = (w & 1) * 32, wn = (w >> 1) * 64;
        const int ach = t & 15;    // E staging: 16B chunk in 256B row seg
        const int arr = t >> 4;    // E staging: base row

        floatx4 acc[2][4] = {};
        float4 er0[4], er1[4];

#define G2_GLOADB(TI, BUF)                                                          \
    {                                                                               \
        const int kk_ = kb + (TI) * BK;                                             \
        _Pragma("unroll")                                                           \
        for (int i = 0; i < 4; ++i)                                                 \
            gload16(&YT[(size_t)(i * 32 + w * 8 + lr) * V + kk_ + 8 * lch],         \
                    &LBIG[BUF][i * 2048 + w * 512]);                                \
    }
#define G2_ELOAD(ER, TI)                                                            \
    {                                                                               \
        const int kk_ = kb + (TI) * BK;                                             \
        _Pragma("unroll")                                                           \
        for (int u = 0; u < 4; ++u)                                                 \
            ER[u] = *(const float4*)&E[(size_t)(m0 + arr + 16 * u) * V + kk_ + ach * 4]; \
    }
#define G2_CONV(ER, BUF)                                                            \
    {                                                                               \
        _Pragma("unroll")                                                           \
        for (int u = 0; u < 4; ++u) {                                               \
            const int row = arr + 16 * u;                                           \
            ushort4 av;                                                             \
            av.x = f2bf(ER[u].x); av.y = f2bf(ER[u].y);                             \
            av.z = f2bf(ER[u].z); av.w = f2bf(ER[u].w);                             \
            *(ushort4*)&LSML[BUF][row * BK + ((ach >> 1) ^ (row & 7)) * 8 + (ach & 1) * 4] = av; \
        }                                                                           \
    }
#define G2_MFMA(pA, pB)                                                             \
    {                                                                               \
        _Pragma("unroll")                                                           \
        for (int kk = 0; kk < BK; kk += 32) {                                       \
            short8 af[2], bfv[4];                                                   \
            _Pragma("unroll")                                                       \
            for (int mi = 0; mi < 2; ++mi) {                                        \
                const int m = wm + mi * 16 + l15;                                   \
                af[mi] = *(const short8*)&pA[m * BK + 8 * (((kk >> 3) + q) ^ (m & 7))]; \
            }                                                                       \
            _Pragma("unroll")                                                       \
            for (int ni = 0; ni < 4; ++ni) {                                        \
                const int n = wn + ni * 16 + l15;                                   \
                bfv[ni] = *(const short8*)&pB[n * BK + 8 * (((kk >> 3) + q) ^ (n & 7))]; \
            }                                                                       \
            _Pragma("unroll")                                                       \
            for (int mi = 0; mi < 2; ++mi)                                          \
                _Pragma("unroll")                                                   \
                for (int ni = 0; ni < 4; ++ni)                                      \
                    acc[mi][ni] = __builtin_amdgcn_mfma_f32_16x16x32_bf16(          \
                        af[mi], bfv[ni], acc[mi][ni], 0, 0, 0);                     \
        }                                                                           \
    }

        G2_ELOAD(er0, 0);
        G2_GLOADB(0, 0);
        G2_ELOAD(er1, 1);
        G2_CONV(er0, 0);
        SWAIT("vmcnt(4) lgkmcnt(0)");
        SBAR();
        SFENCE();

#define G2_BODY(T, PF_ER, CV_ER)                                                    \
    {                                                                               \
        const int t1 = (T) + 1;                                                     \
        const int t2 = ((T) + 2 < NI) ? (T) + 2 : NI - 1;                           \
        const bool pf = t1 < NI;                                                    \
        if (pf) {                                                                   \
            G2_GLOADB(t1, cur ^ 1);                                                 \
            G2_ELOAD(PF_ER, t2);                                                    \
        }                                                                           \
        SFENCE();                                                                   \
        __builtin_amdgcn_s_setprio(1);                                              \
        G2_MFMA((&LSML[cur][0]), (&LBIG[cur][0]));                                  \
        __builtin_amdgcn_s_setprio(0);                                              \
        SFENCE();                                                                   \
        if (pf) {                                                                   \
            G2_CONV(CV_ER, cur ^ 1);                                                \
            SWAIT("vmcnt(4) lgkmcnt(0)");                                           \
            SBAR();                                                                 \
            SFENCE();                                                               \
            cur ^= 1;                                                               \
        }                                                                           \
    }

        int cur = 0;
        for (int tt = 0; tt < NI; tt += 2) {
            G2_BODY(tt, er0, er1);
            G2_BODY(tt + 1, er1, er0);
        }
#undef G2_BODY
#undef G2_MFMA
#undef G2_CONV
#undef G2_ELOAD
#undef G2_GLOADB

        float* Pks = P2 + (size_t)ks * V * C;
#pragma unroll
        for (int mi = 0; mi < 2; ++mi) {
            int mrow = m0 + wm + mi * 16 + q * 4;
#pragma unroll
            for (int ni = 0; ni < 4; ++ni) {
                int n = wn + ni * 16 + l15;
#pragma unroll
                for (int r = 0; r < 4; ++r)
                    Pks[(size_t)(mrow + r) * C + n] = acc[mi][ni][r];
            }
        }
    }

    // ============ phase 4: red2 — last arrival per m-slab sums P2 ============
    __threadfence();
    __syncthreads();
    if (t == 0)
        s_old = __hip_atomic_fetch_add(cnt_m + slab, 1, __ATOMIC_ACQ_REL,
                                       __HIP_MEMORY_SCOPE_AGENT);
    __syncthreads();
    if (s_old == KS - 1) {
        __threadfence();
        const int m0 = slab * 64;
#pragma unroll
        for (int p = 0; p < 8; ++p) {
            const int u = t + 256 * p;          // 0..2047 = 64 rows x 32 float4
            const size_t off = (size_t)(m0 + (u >> 5)) * C + (u & 31) * 4;
            float4 s = {0.f, 0.f, 0.f, 0.f};
#pragma unroll
            for (int kr = 0; kr < KS; ++kr) {
                float4 v = *(const float4*)&P2[(size_t)kr * V * C + off];
                s.x += v.x; s.y += v.y; s.z += v.z; s.w += v.w;
            }
            *(float4*)&out[off] = s;
        }
    }
}

// ---------------------------------------------------------------- launch
extern "C" void kernel_launch(void* const* d_in, const int* in_sizes, int n_in,
                              void* d_out, int out_size, void* d_ws, size_t ws_size,
                              hipStream_t stream) {
    const float* x    = (const float*)d_in[0];
    const float* mass = (const float*)d_in[3];
    const float* ev0  = (const float*)d_in[4];
    const float* ev1  = (const float*)d_in[5];
    const float* E    = (const float*)d_in[6];
    const float* dt   = (const float*)d_in[7];
    float* out = (float*)d_out;

    // ws: cnt (16 KB) | XMT (2 MB) | YT (2 MB) | P1 (16 MB) | P2 (16 MB)
    int* cnt = (int*)d_ws;
    unsigned short* XMT = (unsigned short*)((char*)d_ws + 16384);
    unsigned short* YT  = XMT + (size_t)V * C;
    float* P1 = (float*)(YT + (size_t)V * C);
    float* P2 = P1 + (size_t)KS * C * V;

    hipMemsetAsync(d_ws, 0, 16384, stream);   // zero flags (ws is poison-filled)
    persist<<<NBLK, 256, 0, stream>>>(x, mass, E, ev0, ev1, dt, XMT, YT, P1, P2,
                                      out, cnt);
}